// Round 2
// 608.828 us; speedup vs baseline: 1.2281x; 1.2281x over previous
//
#include <hip/hip_runtime.h>
#include <hip/hip_bf16.h>
#include <math.h>

// Profile-HMM forward (scaled). M=4, B=64, L=512, Q=512, S=26.
//
// Round 8 (resubmit; previous bench died to container-acquire failure, not a
// kernel verdict) = round 7 + operand-swapped MFMA to delete the tr4
// transpose:
//  - compute C[p][s] = Atq-hat @ alpha-hat (A-op = breg rows p, B-op = albuf
//    rows s). A/B operands share the same per-lane layout, so both existing
//    LDS/register images are reused verbatim; only lane roles change:
//    stream sl = lane&15, q-subchunk = quad = lane>>4. MFMA output now lands
//    directly as (1 stream, 4 consecutive p) per lane -> tr4 (40 VALU/wave/
//    step on the serial path) is gone.
//  - S-reduction: one shfl_xor(16) then two psl entries per wave (quad 0/2);
//    wave-0 publisher sums 32 partials (lanes 0..31, halves combined by one
//    shfl_xor(16)) and publishes Sfin[16] as before.
//  - e-prefetch strength-reduced: uniform E4 base + 32-bit per-lane index,
//    +ESTR4 per body; the t+2 clamp only matters for the final body, which
//    the caller passes explicitly (no per-body 64-bit mul / min).

#define MM 4
#define BB 64
#define LL 512
#define QQ 512
#define SS 26
#define ASTR 528   // albuf row stride bytes (16-mult)

typedef float f32x4 __attribute__((ext_vector_type(4)));
typedef int i32x4 __attribute__((ext_vector_type(4)));
typedef int i32x8 __attribute__((ext_vector_type(8)));

__device__ __forceinline__ float bf2f(unsigned short u) {
    return __uint_as_float(((unsigned)u) << 16);
}
__device__ __forceinline__ unsigned short f2bf(float f) {
    unsigned u = __float_as_uint(f);
    u = u + 0x7FFFu + ((u >> 16) & 1u);   // RNE
    return (unsigned short)(u >> 16);
}
__device__ __forceinline__ unsigned char f2fp8(float x) {
    int r = __builtin_amdgcn_cvt_pk_fp8_f32(x, x, 0, false);
    return (unsigned char)(r & 0xFF);
}
__device__ __forceinline__ i32x8 ld32B(const unsigned char* p) {
    i32x4 lo = *(const i32x4*)p;
    i32x4 hi = *(const i32x4*)(p + 16);
    return __builtin_shufflevector(lo, hi, 0, 1, 2, 3, 4, 5, 6, 7);
}
// Barrier that waits only on LDS ops (no vmcnt drain).
// imm 0xC07F: vmcnt=63 (no wait), expcnt=7 (no wait), lgkmcnt=0 (full wait).
__device__ __forceinline__ void barrier_lds() {
    __asm__ __volatile__("" ::: "memory");
    __builtin_amdgcn_s_waitcnt(0xC07F);
    __builtin_amdgcn_s_barrier();
    __asm__ __volatile__("" ::: "memory");
}

// ---------------- preproc (unchanged) ----------------

__global__ void prep_small(const float* __restrict__ il, const float* __restrict__ em,
                           float* __restrict__ pi, float* __restrict__ Bem) {
    int blk = blockIdx.x;
    int m = blk / (QQ + 1);
    int r = blk % (QQ + 1);
    int lane = threadIdx.x;
    if (r < QQ) {
        float x = (lane < SS) ? em[((size_t)m * QQ + r) * SS + lane] : -1e30f;
        float mx = x;
        #pragma unroll
        for (int o = 1; o < 64; o <<= 1) mx = fmaxf(mx, __shfl_xor(mx, o));
        float e = (lane < SS) ? __expf(x - mx) : 0.f;
        float s = e;
        #pragma unroll
        for (int o = 1; o < 64; o <<= 1) s += __shfl_xor(s, o);
        if (lane < SS) Bem[((size_t)m * QQ + r) * SS + lane] = e / s;
    } else {
        float v[8];
        float mx = -1e30f;
        #pragma unroll
        for (int k = 0; k < 8; ++k) { v[k] = il[m * QQ + k * 64 + lane]; mx = fmaxf(mx, v[k]); }
        #pragma unroll
        for (int o = 1; o < 64; o <<= 1) mx = fmaxf(mx, __shfl_xor(mx, o));
        float s = 0.f;
        #pragma unroll
        for (int k = 0; k < 8; ++k) { v[k] = __expf(v[k] - mx); s += v[k]; }
        #pragma unroll
        for (int o = 1; o < 64; o <<= 1) s += __shfl_xor(s, o);
        #pragma unroll
        for (int k = 0; k < 8; ++k) pi[m * QQ + k * 64 + lane] = v[k] / s;
    }
}

__global__ void prep_arow(const float* __restrict__ Al, float* __restrict__ Lrow) {
    int row = blockIdx.x;
    int lane = threadIdx.x;
    const float* p = Al + (size_t)row * QQ;
    float v[8];
    float mx = -1e30f;
    #pragma unroll
    for (int k = 0; k < 8; ++k) { v[k] = p[k * 64 + lane]; mx = fmaxf(mx, v[k]); }
    #pragma unroll
    for (int o = 1; o < 64; o <<= 1) mx = fmaxf(mx, __shfl_xor(mx, o));
    float s = 0.f;
    #pragma unroll
    for (int k = 0; k < 8; ++k) s += __expf(v[k] - mx);
    #pragma unroll
    for (int o = 1; o < 64; o <<= 1) s += __shfl_xor(s, o);
    if (lane == 0) Lrow[row] = mx + __logf(s);
}

// Atq[m][p][q] = fp8(256 * softmax_over_p(A_logits[m][q][:])[p])  (natural q)
__global__ void prep_atq(const float* __restrict__ Al, const float* __restrict__ Lrow,
                         unsigned char* __restrict__ Atq) {
    int bid = blockIdx.x;
    int m = bid >> 3, pb = bid & 7;
    __shared__ unsigned char tile[64][68];
    int l6 = threadIdx.x & 63, g = threadIdx.x >> 6;
    for (int c = 0; c < 8; ++c) {
        #pragma unroll
        for (int r = 0; r < 16; ++r) {
            int ql = g * 16 + r;
            int q = c * 64 + ql;
            float x = Al[((size_t)m * QQ + q) * QQ + pb * 64 + l6];
            tile[ql][l6] = f2fp8(__expf(x - Lrow[m * QQ + q]) * 256.f);
        }
        __syncthreads();
        #pragma unroll
        for (int r = 0; r < 16; ++r) {
            int pr = g * 16 + r;
            Atq[((size_t)m * QQ + pb * 64 + pr) * QQ + c * 64 + l6] = tile[l6][pr];
        }
        __syncthreads();
    }
}

__global__ void prep_e(const float* __restrict__ inp, const float* __restrict__ Bem,
                       unsigned short* __restrict__ E) {
    int bid = blockIdx.x;
    int tc = bid & 7;
    int b = (bid >> 3) & 63;
    int m = bid >> 9;
    int q0 = threadIdx.x;
    float bem0[SS], bem1[SS];
    const float* bp = Bem + (size_t)m * QQ * SS;
    #pragma unroll
    for (int j = 0; j < SS; ++j) bem0[j] = bp[(size_t)q0 * SS + j];
    #pragma unroll
    for (int j = 0; j < SS; ++j) bem1[j] = bp[(size_t)(q0 + 256) * SS + j];
    const float* ip = inp + (((size_t)(m * BB + b)) * LL + tc * 64) * SS;
    for (int lt = 0; lt < 64; ++lt) {
        int t = tc * 64 + lt;
        float a0 = 0.f, a1 = 0.f;
        #pragma unroll
        for (int j = 0; j < SS; ++j) {
            float x = ip[lt * SS + j];
            a0 += x * bem0[j];
            a1 += x * bem1[j];
        }
        size_t o = (((size_t)m * LL + t) * BB + b) * QQ + q0;
        E[o] = f2bf(a0);
        E[o + 256] = f2bf(a1);
    }
}

// ---------------- scan ----------------

__launch_bounds__(1024, 4)
__global__ void hmm_scan(const unsigned short* __restrict__ E,
                         const unsigned char* __restrict__ Atq,
                         const float* __restrict__ pi,
                         float* __restrict__ out) {
    const int c = blockIdx.x;               // 16 clusters
    const int m = c >> 2, bg = c & 3;
    const int tid = threadIdx.x;
    const int lane = tid & 63;
    const int wv = tid >> 6;                // 0..15, owns p = wv*32 .. wv*32+31
    const int sl = lane & 15;               // this lane's stream
    const int quad = lane >> 4;             // q-subchunk / MFMA k-group
    const float LOG256 = 5.545177444479562f;

    __shared__ unsigned char albuf[2][16 * ASTR];   // [parity][s][q] fp8, natural q
    __shared__ float psl[2][16][36];                // [parity][s][2*wave+half] (padded)
    __shared__ float Sfin[2][16];                   // [parity][s] published S_t

    // persistent fragments: this wave's 32 p-rows of fp8(256*A[m]) -> MFMA A-op.
    i32x8 breg[2][4];
    {
        const unsigned char* Ab = Atq + (size_t)m * QQ * QQ;
        #pragma unroll
        for (int h = 0; h < 2; ++h) {
            int p = wv * 32 + h * 16 + sl;
            const unsigned char* rp = Ab + (size_t)p * QQ + quad * 32;
            #pragma unroll
            for (int kc = 0; kc < 4; ++kc)
                breg[h][kc] = ld32B(rp + kc * 128);
        }
    }

    // albuf write offsets: row sl, b32 covering q = wv*32 + h*16 + quad*4 .. +3
    int wq[2];
    #pragma unroll
    for (int h = 0; h < 2; ++h)
        wq[h] = sl * ASTR + wv * 32 + h * 16 + quad * 4;

    const int b = bg * 16 + sl;
    const size_t ebase = (size_t)m * LL * BB * QQ;
    const ushort4* __restrict__ E4 = (const ushort4*)(E + ebase);
    const unsigned ESTR4 = (BB * QQ) >> 2;          // one time-row, ushort4 units
    const unsigned ebq = (unsigned)(b * QQ) >> 2;   // this stream's row base
    const unsigned eoffs0 = (unsigned)(wv * 8 + quad);
    const unsigned eoffs1 = eoffs0 + 4;

    float v[2][4];
    ushort4 ea[2], eb[2];

    // prologue: prefetch e_1 -> ea ; v_0 = pi * e_0
    {
        ea[0] = E4[ebq + ESTR4 + eoffs0];
        ea[1] = E4[ebq + ESTR4 + eoffs1];
        #pragma unroll
        for (int h = 0; h < 2; ++h) {
            int p0 = wv * 32 + h * 16 + quad * 4;
            f32x4 pv = *(const f32x4*)(pi + m * QQ + p0);
            ushort4 e0 = E4[ebq + (h ? eoffs1 : eoffs0)];
            v[h][0] = pv[0] * bf2f(e0.x);
            v[h][1] = pv[1] * bf2f(e0.y);
            v[h][2] = pv[2] * bf2f(e0.z);
            v[h][3] = pv[3] * bf2f(e0.w);
        }
    }

    // lag-2 gain state: lam targets mean quantized value ~128/512 per element.
    float lam = 0.5f;
    float gprev = 1.0f;
    float ll = 0.0f;

    auto body = [&](int t, ushort4 (&ecur)[2], ushort4 (&enxt)[2], unsigned epre) {
        const int par = t & 1;
        // prefetch e_{t+2} (consumed next iteration; never force-drained)
        enxt[0] = E4[epre + eoffs0];
        enxt[1] = E4[epre + eoffs1];

        float g = 128.0f * __builtin_amdgcn_rcpf(lam);
        // alpha-hat_t = fp8(g * v_t), packed 4 bytes -> one b32 per h
        unsigned char* ab = &albuf[par][0];
        #pragma unroll
        for (int h = 0; h < 2; ++h) {
            int d = __builtin_amdgcn_cvt_pk_fp8_f32(g * v[h][0], g * v[h][1], 0, false);
            d = __builtin_amdgcn_cvt_pk_fp8_f32(g * v[h][2], g * v[h][3], d, true);
            *(int*)(ab + wq[h]) = d;
        }
        // per-(wave,quad-pair) partial sum for S_t (own stream sl)
        float ps = (v[0][0] + v[0][1]) + (v[0][2] + v[0][3])
                 + (v[1][0] + v[1][1]) + (v[1][2] + v[1][3]);
        ps += __shfl_xor(ps, 16);
        if ((quad & 1) == 0) psl[par][sl][2 * wv + (quad >> 1)] = ps;

        ll -= __logf(g) + LOG256;   // exact: ll = log S_L - sum log(256 g_t)

        barrier_lds();              // LDS-only wait; no vmcnt drain

        // wave 0 publishes S_t for step t+1's consumers (32 partials/stream)
        if (wv == 0 && lane < 32) {
            const f32x4* pr = (const f32x4*)&psl[par][sl][(lane >> 4) * 16];
            f32x4 s0 = pr[0], s1 = pr[1], s2 = pr[2], s3 = pr[3];
            f32x4 ss4 = (s0 + s1) + (s2 + s3);
            float ss = (ss4[0] + ss4[1]) + (ss4[2] + ss4[3]);
            ss += __shfl_xor(ss, 16);
            if (lane < 16) Sfin[par][sl] = ss;
        }
        // lag-2 lambda update: lam_{t+1} = 256*g_t * (256*g_{t-1}*S_{t-1}*0.5) * 0.5
        if (t == 0) {
            lam = 16384.0f;
        } else {
            float Sp = Sfin[par ^ 1][sl];   // S_{t-1}, published during body(t-1)
            lam = 16384.0f * g * gprev * Sp;
        }
        gprev = g;

        // r^T = A-hat^T @ alpha-hat^T : 8 MX-fp8 MFMA (K=128), operand-swapped
        // so C[row=p-quad, col=stream] lands as (1 stream, 4 consecutive p)/lane.
        f32x4 acc[2];
        acc[0] = (f32x4){0.f, 0.f, 0.f, 0.f};
        acc[1] = (f32x4){0.f, 0.f, 0.f, 0.f};
        const unsigned char* ar = &albuf[par][0] + sl * ASTR + quad * 32;
        #pragma unroll
        for (int kc = 0; kc < 4; ++kc) {
            i32x8 af = ld32B(ar + kc * 128);
            #pragma unroll
            for (int h = 0; h < 2; ++h)
                acc[h] = __builtin_amdgcn_mfma_scale_f32_16x16x128_f8f6f4(
                    breg[h][kc], af, acc[h], 0, 0,
                    0, 0x7F7F7F7F, 0, 0x7F7F7F7F);   // unit e8m0 scales
        }
        // no transpose needed: lane already owns (stream sl, p = base+quad*4+j)
        #pragma unroll
        for (int h = 0; h < 2; ++h) {
            v[h][0] = acc[h][0] * bf2f(ecur[h].x);
            v[h][1] = acc[h][1] * bf2f(ecur[h].y);
            v[h][2] = acc[h][2] * bf2f(ecur[h].z);
            v[h][3] = acc[h][3] * bf2f(ecur[h].w);
        }
    };

    // e-prefetch index: row t+2, strength-reduced (+ESTR4 per body).
    unsigned epre = ebq + 2 * ESTR4;
    for (int t = 0; t < LL - 2; t += 2) {
        body(t, ea, eb, epre); epre += ESTR4;
        body(t + 1, eb, ea, epre); epre += ESTR4;
    }
    // final body: t+2 would be out of range; re-prefetch last row (harmless).
    body(LL - 2, ea, eb, ebq + (unsigned)(LL - 1) * ESTR4);

    // epilogue: exact S_511 (full reduction; one heavyweight barrier is fine)
    {
        float ps = (v[0][0] + v[0][1]) + (v[0][2] + v[0][3])
                 + (v[1][0] + v[1][1]) + (v[1][2] + v[1][3]);
        ps += __shfl_xor(ps, 16);
        if ((quad & 1) == 0) psl[1][sl][2 * wv + (quad >> 1)] = ps;
        __syncthreads();
        if (wv == 0 && lane < 16) {
            const f32x4* pr = (const f32x4*)&psl[1][sl][0];
            f32x4 s0 = (pr[0] + pr[1]) + (pr[2] + pr[3]);
            f32x4 s1 = (pr[4] + pr[5]) + (pr[6] + pr[7]);
            f32x4 ss = s0 + s1;
            float S = (ss[0] + ss[1]) + (ss[2] + ss[3]);
            out[m * BB + bg * 16 + sl] = ll + __logf(S);
        }
    }
}

// ---------------- host ----------------

extern "C" void kernel_launch(void* const* d_in, const int* in_sizes, int n_in,
                              void* d_out, int out_size, void* d_ws, size_t ws_size,
                              hipStream_t stream) {
    const float* inputs = (const float*)d_in[0];
    const float* A_logits = (const float*)d_in[1];
    const float* init_logits = (const float*)d_in[2];
    const float* em_logits = (const float*)d_in[3];
    float* out = (float*)d_out;

    char* ws = (char*)d_ws;
    size_t off = 0;
    unsigned short* E = (unsigned short*)(ws + off);  off += (size_t)MM * LL * BB * QQ * 2;  // 134 MB
    unsigned char* Atq = (unsigned char*)(ws + off);  off += (size_t)MM * QQ * QQ;           // 1 MB
    float* Bem = (float*)(ws + off);                  off += (size_t)MM * QQ * SS * 4;
    float* pi = (float*)(ws + off);                   off += (size_t)MM * QQ * 4;
    float* Lrow = (float*)(ws + off);                 off += (size_t)MM * QQ * 4;

    if (ws_size < off) {
        (void)hipMemsetAsync(d_out, 0, (size_t)out_size * sizeof(float), stream);
        return;
    }

    prep_small<<<dim3(MM * (QQ + 1)), dim3(64), 0, stream>>>(init_logits, em_logits, pi, Bem);
    prep_arow<<<dim3(MM * QQ), dim3(64), 0, stream>>>(A_logits, Lrow);
    prep_atq<<<dim3(MM * 8), dim3(256), 0, stream>>>(A_logits, Lrow, Atq);
    prep_e<<<dim3(MM * BB * 8), dim3(256), 0, stream>>>(inputs, Bem, E);
    hmm_scan<<<dim3(16), dim3(1024), 0, stream>>>(E, Atq, pi, out);
}

// Round 3
// 591.079 us; speedup vs baseline: 1.2650x; 1.0300x over previous
//
#include <hip/hip_runtime.h>
#include <hip/hip_bf16.h>
#include <math.h>

// Profile-HMM forward (scaled). M=4, B=64, L=512, Q=512, S=26.
//
// Round 9 = round 8 + 8-wave restructure to halve LDS read bandwidth:
//  - 16 clusters x 512 threads (8 waves). Each wave owns 64 p-rows
//    (breg[4][4], 4 h-groups of 16 p) instead of 32. The MFMA B-operand
//    (albuf q-chunk, 2 KB/kc) is now reused by 4 MFMAs per read instead
//    of 2 -> per-CU-step LDS reads drop 128 KB -> 64 KB (was ~1000 cyc of
//    LDS BW, co-critical with the ~1100 cyc MFMA phase). MFMA count and
//    total VALU per CU-step unchanged; per-wave ILP doubles (4 acc chains).
//  - psl shrinks to 16 partials/stream (8 waves x 2); publisher sums them
//    directly (no trailing shfl).
//  - everything else (operand-swapped MX-fp8 MFMA, lag-2 gain, LDS-only
//    barrier, strength-reduced e-prefetch) carried over from round 8.

#define MM 4
#define BB 64
#define LL 512
#define QQ 512
#define SS 26
#define ASTR 528   // albuf row stride bytes (16-mult)

typedef float f32x4 __attribute__((ext_vector_type(4)));
typedef int i32x4 __attribute__((ext_vector_type(4)));
typedef int i32x8 __attribute__((ext_vector_type(8)));

__device__ __forceinline__ float bf2f(unsigned short u) {
    return __uint_as_float(((unsigned)u) << 16);
}
__device__ __forceinline__ unsigned short f2bf(float f) {
    unsigned u = __float_as_uint(f);
    u = u + 0x7FFFu + ((u >> 16) & 1u);   // RNE
    return (unsigned short)(u >> 16);
}
__device__ __forceinline__ unsigned char f2fp8(float x) {
    int r = __builtin_amdgcn_cvt_pk_fp8_f32(x, x, 0, false);
    return (unsigned char)(r & 0xFF);
}
__device__ __forceinline__ i32x8 ld32B(const unsigned char* p) {
    i32x4 lo = *(const i32x4*)p;
    i32x4 hi = *(const i32x4*)(p + 16);
    return __builtin_shufflevector(lo, hi, 0, 1, 2, 3, 4, 5, 6, 7);
}
// Barrier that waits only on LDS ops (no vmcnt drain).
// imm 0xC07F: vmcnt=63 (no wait), expcnt=7 (no wait), lgkmcnt=0 (full wait).
__device__ __forceinline__ void barrier_lds() {
    __asm__ __volatile__("" ::: "memory");
    __builtin_amdgcn_s_waitcnt(0xC07F);
    __builtin_amdgcn_s_barrier();
    __asm__ __volatile__("" ::: "memory");
}

// ---------------- preproc (unchanged) ----------------

__global__ void prep_small(const float* __restrict__ il, const float* __restrict__ em,
                           float* __restrict__ pi, float* __restrict__ Bem) {
    int blk = blockIdx.x;
    int m = blk / (QQ + 1);
    int r = blk % (QQ + 1);
    int lane = threadIdx.x;
    if (r < QQ) {
        float x = (lane < SS) ? em[((size_t)m * QQ + r) * SS + lane] : -1e30f;
        float mx = x;
        #pragma unroll
        for (int o = 1; o < 64; o <<= 1) mx = fmaxf(mx, __shfl_xor(mx, o));
        float e = (lane < SS) ? __expf(x - mx) : 0.f;
        float s = e;
        #pragma unroll
        for (int o = 1; o < 64; o <<= 1) s += __shfl_xor(s, o);
        if (lane < SS) Bem[((size_t)m * QQ + r) * SS + lane] = e / s;
    } else {
        float v[8];
        float mx = -1e30f;
        #pragma unroll
        for (int k = 0; k < 8; ++k) { v[k] = il[m * QQ + k * 64 + lane]; mx = fmaxf(mx, v[k]); }
        #pragma unroll
        for (int o = 1; o < 64; o <<= 1) mx = fmaxf(mx, __shfl_xor(mx, o));
        float s = 0.f;
        #pragma unroll
        for (int k = 0; k < 8; ++k) { v[k] = __expf(v[k] - mx); s += v[k]; }
        #pragma unroll
        for (int o = 1; o < 64; o <<= 1) s += __shfl_xor(s, o);
        #pragma unroll
        for (int k = 0; k < 8; ++k) pi[m * QQ + k * 64 + lane] = v[k] / s;
    }
}

__global__ void prep_arow(const float* __restrict__ Al, float* __restrict__ Lrow) {
    int row = blockIdx.x;
    int lane = threadIdx.x;
    const float* p = Al + (size_t)row * QQ;
    float v[8];
    float mx = -1e30f;
    #pragma unroll
    for (int k = 0; k < 8; ++k) { v[k] = p[k * 64 + lane]; mx = fmaxf(mx, v[k]); }
    #pragma unroll
    for (int o = 1; o < 64; o <<= 1) mx = fmaxf(mx, __shfl_xor(mx, o));
    float s = 0.f;
    #pragma unroll
    for (int k = 0; k < 8; ++k) s += __expf(v[k] - mx);
    #pragma unroll
    for (int o = 1; o < 64; o <<= 1) s += __shfl_xor(s, o);
    if (lane == 0) Lrow[row] = mx + __logf(s);
}

// Atq[m][p][q] = fp8(256 * softmax_over_p(A_logits[m][q][:])[p])  (natural q)
__global__ void prep_atq(const float* __restrict__ Al, const float* __restrict__ Lrow,
                         unsigned char* __restrict__ Atq) {
    int bid = blockIdx.x;
    int m = bid >> 3, pb = bid & 7;
    __shared__ unsigned char tile[64][68];
    int l6 = threadIdx.x & 63, g = threadIdx.x >> 6;
    for (int c = 0; c < 8; ++c) {
        #pragma unroll
        for (int r = 0; r < 16; ++r) {
            int ql = g * 16 + r;
            int q = c * 64 + ql;
            float x = Al[((size_t)m * QQ + q) * QQ + pb * 64 + l6];
            tile[ql][l6] = f2fp8(__expf(x - Lrow[m * QQ + q]) * 256.f);
        }
        __syncthreads();
        #pragma unroll
        for (int r = 0; r < 16; ++r) {
            int pr = g * 16 + r;
            Atq[((size_t)m * QQ + pb * 64 + pr) * QQ + c * 64 + l6] = tile[l6][pr];
        }
        __syncthreads();
    }
}

__global__ void prep_e(const float* __restrict__ inp, const float* __restrict__ Bem,
                       unsigned short* __restrict__ E) {
    int bid = blockIdx.x;
    int tc = bid & 7;
    int b = (bid >> 3) & 63;
    int m = bid >> 9;
    int q0 = threadIdx.x;
    float bem0[SS], bem1[SS];
    const float* bp = Bem + (size_t)m * QQ * SS;
    #pragma unroll
    for (int j = 0; j < SS; ++j) bem0[j] = bp[(size_t)q0 * SS + j];
    #pragma unroll
    for (int j = 0; j < SS; ++j) bem1[j] = bp[(size_t)(q0 + 256) * SS + j];
    const float* ip = inp + (((size_t)(m * BB + b)) * LL + tc * 64) * SS;
    for (int lt = 0; lt < 64; ++lt) {
        int t = tc * 64 + lt;
        float a0 = 0.f, a1 = 0.f;
        #pragma unroll
        for (int j = 0; j < SS; ++j) {
            float x = ip[lt * SS + j];
            a0 += x * bem0[j];
            a1 += x * bem1[j];
        }
        size_t o = (((size_t)m * LL + t) * BB + b) * QQ + q0;
        E[o] = f2bf(a0);
        E[o + 256] = f2bf(a1);
    }
}

// ---------------- scan ----------------

__launch_bounds__(512, 2)
__global__ void hmm_scan(const unsigned short* __restrict__ E,
                         const unsigned char* __restrict__ Atq,
                         const float* __restrict__ pi,
                         float* __restrict__ out) {
    const int c = blockIdx.x;               // 16 clusters
    const int m = c >> 2, bg = c & 3;
    const int tid = threadIdx.x;
    const int lane = tid & 63;
    const int wv = tid >> 6;                // 0..7, owns p = wv*64 .. wv*64+63
    const int sl = lane & 15;               // this lane's stream
    const int quad = lane >> 4;             // q-subchunk / MFMA k-group
    const float LOG256 = 5.545177444479562f;

    __shared__ unsigned char albuf[2][16 * ASTR];       // [parity][s][q] fp8
    __shared__ __align__(16) float psl[2][16][20];      // [parity][s][2*wave+half]
    __shared__ float Sfin[2][16];                       // [parity][s] published S_t

    // persistent fragments: this wave's 64 p-rows of fp8(256*A[m]) -> MFMA A-op.
    i32x8 breg[4][4];
    {
        const unsigned char* Ab = Atq + (size_t)m * QQ * QQ;
        #pragma unroll
        for (int h = 0; h < 4; ++h) {
            int p = wv * 64 + h * 16 + sl;
            const unsigned char* rp = Ab + (size_t)p * QQ + quad * 32;
            #pragma unroll
            for (int kc = 0; kc < 4; ++kc)
                breg[h][kc] = ld32B(rp + kc * 128);
        }
    }

    // albuf write offsets: row sl, b32 covering q = wv*64 + h*16 + quad*4 .. +3
    int wq[4];
    #pragma unroll
    for (int h = 0; h < 4; ++h)
        wq[h] = sl * ASTR + wv * 64 + h * 16 + quad * 4;

    const int b = bg * 16 + sl;
    const size_t ebase = (size_t)m * LL * BB * QQ;
    const ushort4* __restrict__ E4 = (const ushort4*)(E + ebase);
    const unsigned ESTR4 = (BB * QQ) >> 2;          // one time-row, ushort4 units
    const unsigned ebq = (unsigned)(b * QQ) >> 2;   // this stream's row base
    unsigned eoffs[4];
    #pragma unroll
    for (int h = 0; h < 4; ++h) eoffs[h] = (unsigned)(wv * 16 + h * 4 + quad);

    float v[4][4];
    ushort4 ea[4], eb[4];

    // prologue: prefetch e_1 -> ea ; v_0 = pi * e_0
    {
        #pragma unroll
        for (int h = 0; h < 4; ++h) ea[h] = E4[ebq + ESTR4 + eoffs[h]];
        #pragma unroll
        for (int h = 0; h < 4; ++h) {
            int p0 = wv * 64 + h * 16 + quad * 4;
            f32x4 pv = *(const f32x4*)(pi + m * QQ + p0);
            ushort4 e0 = E4[ebq + eoffs[h]];
            v[h][0] = pv[0] * bf2f(e0.x);
            v[h][1] = pv[1] * bf2f(e0.y);
            v[h][2] = pv[2] * bf2f(e0.z);
            v[h][3] = pv[3] * bf2f(e0.w);
        }
    }

    // lag-2 gain state: lam targets mean quantized value ~128/512 per element.
    float lam = 0.5f;
    float gprev = 1.0f;
    float ll = 0.0f;

    auto body = [&](int t, ushort4 (&ecur)[4], ushort4 (&enxt)[4], unsigned epre) {
        const int par = t & 1;
        // prefetch e_{t+2} (consumed next iteration; never force-drained)
        #pragma unroll
        for (int h = 0; h < 4; ++h) enxt[h] = E4[epre + eoffs[h]];

        float g = 128.0f * __builtin_amdgcn_rcpf(lam);
        // alpha-hat_t = fp8(g * v_t), packed 4 bytes -> one b32 per h
        unsigned char* ab = &albuf[par][0];
        #pragma unroll
        for (int h = 0; h < 4; ++h) {
            int d = __builtin_amdgcn_cvt_pk_fp8_f32(g * v[h][0], g * v[h][1], 0, false);
            d = __builtin_amdgcn_cvt_pk_fp8_f32(g * v[h][2], g * v[h][3], d, true);
            *(int*)(ab + wq[h]) = d;
        }
        // per-(wave,quad-pair) partial sum for S_t (own stream sl)
        float ps = ((v[0][0] + v[0][1]) + (v[0][2] + v[0][3]))
                 + ((v[1][0] + v[1][1]) + (v[1][2] + v[1][3]))
                 + ((v[2][0] + v[2][1]) + (v[2][2] + v[2][3]))
                 + ((v[3][0] + v[3][1]) + (v[3][2] + v[3][3]));
        ps += __shfl_xor(ps, 16);
        if ((quad & 1) == 0) psl[par][sl][2 * wv + (quad >> 1)] = ps;

        ll -= __logf(g) + LOG256;   // exact: ll = log S_L - sum log(256 g_t)

        barrier_lds();              // LDS-only wait; no vmcnt drain

        // wave 0 publishes S_t for step t+1's consumers (16 partials/stream)
        if (wv == 0 && lane < 16) {
            const f32x4* pr = (const f32x4*)&psl[par][lane][0];
            f32x4 ss4 = (pr[0] + pr[1]) + (pr[2] + pr[3]);
            Sfin[par][lane] = (ss4[0] + ss4[1]) + (ss4[2] + ss4[3]);
        }
        // lag-2 lambda update: lam_{t+1} = 256*g_t * (256*g_{t-1}*S_{t-1}*0.5) * 0.5
        if (t == 0) {
            lam = 16384.0f;
        } else {
            float Sp = Sfin[par ^ 1][sl];   // S_{t-1}, published during body(t-1)
            lam = 16384.0f * g * gprev * Sp;
        }
        gprev = g;

        // r^T = A-hat^T @ alpha-hat^T : 16 MX-fp8 MFMA (K=128), operand-swapped;
        // each albuf chunk read feeds 4 MFMAs (4 h-groups) -> half the LDS BW.
        f32x4 acc[4];
        #pragma unroll
        for (int h = 0; h < 4; ++h) acc[h] = (f32x4){0.f, 0.f, 0.f, 0.f};
        const unsigned char* ar = &albuf[par][0] + sl * ASTR + quad * 32;
        #pragma unroll
        for (int kc = 0; kc < 4; ++kc) {
            i32x8 af = ld32B(ar + kc * 128);
            #pragma unroll
            for (int h = 0; h < 4; ++h)
                acc[h] = __builtin_amdgcn_mfma_scale_f32_16x16x128_f8f6f4(
                    breg[h][kc], af, acc[h], 0, 0,
                    0, 0x7F7F7F7F, 0, 0x7F7F7F7F);   // unit e8m0 scales
        }
        // lane owns (stream sl, p = wv*64 + h*16 + quad*4 + j)
        #pragma unroll
        for (int h = 0; h < 4; ++h) {
            v[h][0] = acc[h][0] * bf2f(ecur[h].x);
            v[h][1] = acc[h][1] * bf2f(ecur[h].y);
            v[h][2] = acc[h][2] * bf2f(ecur[h].z);
            v[h][3] = acc[h][3] * bf2f(ecur[h].w);
        }
    };

    // e-prefetch index: row t+2, strength-reduced (+ESTR4 per body).
    unsigned epre = ebq + 2 * ESTR4;
    for (int t = 0; t < LL - 2; t += 2) {
        body(t, ea, eb, epre); epre += ESTR4;
        body(t + 1, eb, ea, epre); epre += ESTR4;
    }
    // final body: t+2 would be out of range; re-prefetch last row (harmless).
    body(LL - 2, ea, eb, ebq + (unsigned)(LL - 1) * ESTR4);

    // epilogue: exact S_511 (full reduction; one heavyweight barrier is fine)
    {
        float ps = ((v[0][0] + v[0][1]) + (v[0][2] + v[0][3]))
                 + ((v[1][0] + v[1][1]) + (v[1][2] + v[1][3]))
                 + ((v[2][0] + v[2][1]) + (v[2][2] + v[2][3]))
                 + ((v[3][0] + v[3][1]) + (v[3][2] + v[3][3]));
        ps += __shfl_xor(ps, 16);
        if ((quad & 1) == 0) psl[1][sl][2 * wv + (quad >> 1)] = ps;
        __syncthreads();
        if (wv == 0 && lane < 16) {
            const f32x4* pr = (const f32x4*)&psl[1][lane][0];
            f32x4 ss4 = (pr[0] + pr[1]) + (pr[2] + pr[3]);
            float S = (ss4[0] + ss4[1]) + (ss4[2] + ss4[3]);
            out[m * BB + bg * 16 + lane] = ll + __logf(S);
        }
    }
}

// ---------------- host ----------------

extern "C" void kernel_launch(void* const* d_in, const int* in_sizes, int n_in,
                              void* d_out, int out_size, void* d_ws, size_t ws_size,
                              hipStream_t stream) {
    const float* inputs = (const float*)d_in[0];
    const float* A_logits = (const float*)d_in[1];
    const float* init_logits = (const float*)d_in[2];
    const float* em_logits = (const float*)d_in[3];
    float* out = (float*)d_out;

    char* ws = (char*)d_ws;
    size_t off = 0;
    unsigned short* E = (unsigned short*)(ws + off);  off += (size_t)MM * LL * BB * QQ * 2;  // 134 MB
    unsigned char* Atq = (unsigned char*)(ws + off);  off += (size_t)MM * QQ * QQ;           // 1 MB
    float* Bem = (float*)(ws + off);                  off += (size_t)MM * QQ * SS * 4;
    float* pi = (float*)(ws + off);                   off += (size_t)MM * QQ * 4;
    float* Lrow = (float*)(ws + off);                 off += (size_t)MM * QQ * 4;

    if (ws_size < off) {
        (void)hipMemsetAsync(d_out, 0, (size_t)out_size * sizeof(float), stream);
        return;
    }

    prep_small<<<dim3(MM * (QQ + 1)), dim3(64), 0, stream>>>(init_logits, em_logits, pi, Bem);
    prep_arow<<<dim3(MM * QQ), dim3(64), 0, stream>>>(A_logits, Lrow);
    prep_atq<<<dim3(MM * 8), dim3(256), 0, stream>>>(A_logits, Lrow, Atq);
    prep_e<<<dim3(MM * BB * 8), dim3(256), 0, stream>>>(inputs, Bem, E);
    hmm_scan<<<dim3(16), dim3(512), 0, stream>>>(E, Atq, pi, out);
}